// Round 11
// baseline (238.954 us; speedup 1.0000x reference)
//
#include <hip/hip_runtime.h>
#include <hip/hip_fp16.h>

#define N_NODES 50000
#define N_EDGES 800000
#define F 128
#define ALPHA 0.5f
#define BN_EPS 1e-5f
#define NB_SCAN ((N_NODES + 255) / 256)   // 196
#define GEMM_NBLK ((N_NODES + 63) / 64)   // 782
#define NGRP 8
#define GRP_ROWS (N_NODES / NGRP)         // 6250
#define NCHUNK 64
#define CHUNK_I4 (N_EDGES / NCHUNK / 4)   // 3125 int4 per chunk (12500 edges)
#define PREP_THREADS 1024
#define NB_X2H ((N_NODES * F / 8 + PREP_THREADS - 1) / PREP_THREADS)  // 782
#define NB_PB 6
#define NB_HIST (NGRP * NCHUNK)           // 512

typedef _Float16 half8_t __attribute__((ext_vector_type(8)));
typedef float floatx4 __attribute__((ext_vector_type(4)));

union H8 { uint4 u; __half2 h2[4]; };

// ---------------- fused prep: x->fp16 | pack B | LDS-hist counting ----------------
__global__ __launch_bounds__(PREP_THREADS) void prep_kernel(
        const float* __restrict__ x, __half* __restrict__ xh,
        const float* __restrict__ W1, const float* __restrict__ W2,
        const float* __restrict__ W3, _Float16* __restrict__ Bp,
        const int* __restrict__ row, int* __restrict__ subhist) {
    int bid = blockIdx.x;
    if (bid < NB_X2H) {
        int idx = bid * PREP_THREADS + threadIdx.x;   // one per 8 elems
        if (idx < N_NODES * F / 8) {
            float4 f0 = ((const float4*)x)[idx * 2];
            float4 f1 = ((const float4*)x)[idx * 2 + 1];
            H8 o;
            o.h2[0] = __float22half2_rn(make_float2(f0.x, f0.y));
            o.h2[1] = __float22half2_rn(make_float2(f0.z, f0.w));
            o.h2[2] = __float22half2_rn(make_float2(f1.x, f1.y));
            o.h2[3] = __float22half2_rn(make_float2(f1.z, f1.w));
            ((uint4*)xh)[idx] = o.u;
        }
    } else if (bid < NB_X2H + NB_PB) {
        // B[k][n] = W[n][k]; lane holds B[k0+(lane>>4)*8+j][n0*16+(lane&15)]
        int idx = (bid - NB_X2H) * PREP_THREADS + threadIdx.x;   // 3*2048 = 6144
        int layer = idx >> 11;
        int r = idx & 2047;
        int t = r >> 6, lane = r & 63;
        int s = t >> 3, n0 = t & 7;
        int n = n0 * 16 + (lane & 15);
        int k = s * 32 + (lane >> 4) * 8;
        const float* W = (layer == 0) ? W1 : (layer == 1) ? W2 : W3;
        float4 f0 = *(const float4*)(W + n * 128 + k);
        float4 f1 = *(const float4*)(W + n * 128 + k + 4);
        _Float16* dst = Bp + (size_t)layer * 32768 + (size_t)r * 8;
        dst[0] = (_Float16)f0.x; dst[1] = (_Float16)f0.y;
        dst[2] = (_Float16)f0.z; dst[3] = (_Float16)f0.w;
        dst[4] = (_Float16)f1.x; dst[5] = (_Float16)f1.y;
        dst[6] = (_Float16)f1.z; dst[7] = (_Float16)f1.w;
    } else {
        // subhist[c][i] = #edges in chunk c with row i (row-group g only)
        int t = bid - (NB_X2H + NB_PB);
        int g = t & 7, c = t >> 3;
        int rlo = g * GRP_ROWS;
        __shared__ int hist[GRP_ROWS];
        for (int j = threadIdx.x; j < GRP_ROWS; j += PREP_THREADS) hist[j] = 0;
        __syncthreads();
        const int4* r4 = (const int4*)row;
        for (int v = c * CHUNK_I4 + threadIdx.x; v < (c + 1) * CHUNK_I4;
             v += PREP_THREADS) {
            int4 rr = r4[v];
            if ((unsigned)(rr.x - rlo) < GRP_ROWS) atomicAdd(&hist[rr.x - rlo], 1);
            if ((unsigned)(rr.y - rlo) < GRP_ROWS) atomicAdd(&hist[rr.y - rlo], 1);
            if ((unsigned)(rr.z - rlo) < GRP_ROWS) atomicAdd(&hist[rr.z - rlo], 1);
            if ((unsigned)(rr.w - rlo) < GRP_ROWS) atomicAdd(&hist[rr.w - rlo], 1);
        }
        __syncthreads();
        for (int j = threadIdx.x; j < GRP_ROWS; j += PREP_THREADS)
            subhist[(size_t)c * N_NODES + rlo + j] = hist[j];
    }
}

// ---------------- scan: chunk-offsets (in place) + deg/dinv + block scan ----------------

__global__ void scan_block(int* __restrict__ subhist, int* __restrict__ localscan,
                           int* __restrict__ blocksum, float* __restrict__ dinv) {
    __shared__ int s[256];
    int i = blockIdx.x * 256 + threadIdx.x;
    int deg = 0;
    if (i < N_NODES) {
        for (int c = 0; c < NCHUNK; ++c) {
            int t = subhist[(size_t)c * N_NODES + i];
            subhist[(size_t)c * N_NODES + i] = deg;   // exclusive prefix over chunks
            deg += t;
        }
        dinv[i] = deg > 0 ? rsqrtf((float)deg) : 0.f;
    }
    s[threadIdx.x] = deg;
    __syncthreads();
    for (int off = 1; off < 256; off <<= 1) {
        int t = (threadIdx.x >= off) ? s[threadIdx.x - off] : 0;
        __syncthreads();
        s[threadIdx.x] += t;
        __syncthreads();
    }
    if (i < N_NODES) localscan[i] = s[threadIdx.x];
    if (threadIdx.x == 255) blocksum[blockIdx.x] = s[255];
}

__global__ void scan_add_tops(const int* __restrict__ localscan,
                              const int* __restrict__ blocksum,
                              int* __restrict__ rowptr) {
    __shared__ int s[256];
    int v = (threadIdx.x < NB_SCAN) ? blocksum[threadIdx.x] : 0;
    s[threadIdx.x] = v;
    __syncthreads();
    for (int off = 1; off < 256; off <<= 1) {
        int t = (threadIdx.x >= off) ? s[threadIdx.x - off] : 0;
        __syncthreads();
        s[threadIdx.x] += t;
        __syncthreads();
    }
    int base = (blockIdx.x > 0) ? s[blockIdx.x - 1] : 0;
    int i = blockIdx.x * 256 + threadIdx.x;
    if (i < N_NODES) rowptr[i + 1] = localscan[i] + base;
    if (i == 0) rowptr[0] = 0;
}

// ---------------- fill: LDS-cursor counting-sort scatter (no global atomics) ----------------

__global__ __launch_bounds__(PREP_THREADS) void fill_kernel(
        const int* __restrict__ row, const int* __restrict__ col,
        const int* __restrict__ rowptr, const int* __restrict__ chunkoff,
        const float* __restrict__ dinv, unsigned int* __restrict__ colwt) {
    int t = blockIdx.x;           // 512 blocks: g = t&7, c = t>>3
    int g = t & 7, c = t >> 3;
    int rlo = g * GRP_ROWS;
    __shared__ int cur[GRP_ROWS];
    for (int j = threadIdx.x; j < GRP_ROWS; j += PREP_THREADS)
        cur[j] = rowptr[rlo + j] + chunkoff[(size_t)c * N_NODES + rlo + j];
    __syncthreads();
    const int4* r4 = (const int4*)row;
    const int4* c4 = (const int4*)col;
    for (int v = c * CHUNK_I4 + threadIdx.x; v < (c + 1) * CHUNK_I4;
         v += PREP_THREADS) {
        int4 rr = r4[v];
        int4 cc = c4[v];
        int rs[4] = {rr.x, rr.y, rr.z, rr.w};
        int cs[4] = {cc.x, cc.y, cc.z, cc.w};
        #pragma unroll
        for (int k = 0; k < 4; ++k) {
            if ((unsigned)(rs[k] - rlo) < GRP_ROWS) {
                int pos = atomicAdd(&cur[rs[k] - rlo], 1);
                unsigned int hb = __half_as_ushort(__float2half(dinv[cs[k]]));
                colwt[pos] = (unsigned int)cs[k] | (hb << 16);
            }
        }
    }
}

// ---------------- fused high-pass + MFMA GEMM (one layer per launch) ----------------
// Phase 1 (per wave, 16 own rows): hp row -> fp16 -> LDS (XOR-swizzled chunks).
// Phase 2 (same wave): MFMA A from own LDS rows, B from packed Bp; bias; store.
// USEBN: apply prev-layer BN+ReLU to gathered input. MODE 0: fp16 out + BN
// partials; MODE 1: f32 out, no stats. No inter-wave LDS sharing -> no barrier
// between phases.
template <int USEBN, int MODE>
__global__ __launch_bounds__(256) void fused_kernel(
        const __half* __restrict__ h,
        const float* __restrict__ scale, const float* __restrict__ shift,
        const float* __restrict__ dinv, const int* __restrict__ rowptr,
        const unsigned int* __restrict__ colwt,
        const _Float16* __restrict__ Bp, const float* __restrict__ bias,
        void* __restrict__ outv, float* __restrict__ partial) {
    __shared__ uint4 sA[64 * 16];          // 64 rows x 16 swizzled 16B chunks
    __shared__ float st_s[4][128];
    __shared__ float st_q[4][128];
    int tid = threadIdx.x;
    int w = tid >> 6, lane = tid & 63;
    int q = lane >> 4, l = lane & 15;
    int row0 = blockIdx.x * 64 + w * 16;
    bool active = row0 < N_NODES;          // M % 16 == 0: all-or-nothing per wave

    const char* hb = (const char*)h;
    int loff = l * 16;

    if (active) {
        float sc[8], sh[8];
        if (USEBN) {
            float4 a0 = ((const float4*)scale)[l * 2];
            float4 a1 = ((const float4*)scale)[l * 2 + 1];
            float4 b0 = ((const float4*)shift)[l * 2];
            float4 b1 = ((const float4*)shift)[l * 2 + 1];
            sc[0] = a0.x; sc[1] = a0.y; sc[2] = a0.z; sc[3] = a0.w;
            sc[4] = a1.x; sc[5] = a1.y; sc[6] = a1.z; sc[7] = a1.w;
            sh[0] = b0.x; sh[1] = b0.y; sh[2] = b0.z; sh[3] = b0.w;
            sh[4] = b1.x; sh[5] = b1.y; sh[6] = b1.z; sh[7] = b1.w;
        }
        // ---------- phase 1: hp for rows row0..row0+15 ----------
        for (int rr = 0; rr < 16; ++rr) {
            int i = row0 + rr;
            int e0 = rowptr[i], e1 = rowptr[i + 1];
            float acc[8] = {0.f, 0.f, 0.f, 0.f, 0.f, 0.f, 0.f, 0.f};
            int e = e0 + q;
            for (; e + 14 < e1; e += 16) {   // 4 edges per quarter in flight
                unsigned int cw0 = colwt[e];
                unsigned int cw1 = colwt[e + 4];
                unsigned int cw2 = colwt[e + 8];
                unsigned int cw3 = colwt[e + 12];
                H8 r0, r1, r2, r3;
                r0.u = *(const uint4*)(hb + (size_t)(cw0 & 0xffffu) * 256 + loff);
                r1.u = *(const uint4*)(hb + (size_t)(cw1 & 0xffffu) * 256 + loff);
                r2.u = *(const uint4*)(hb + (size_t)(cw2 & 0xffffu) * 256 + loff);
                r3.u = *(const uint4*)(hb + (size_t)(cw3 & 0xffffu) * 256 + loff);
                float w0 = __half2float(__ushort_as_half((unsigned short)(cw0 >> 16)));
                float w1 = __half2float(__ushort_as_half((unsigned short)(cw1 >> 16)));
                float w2 = __half2float(__ushort_as_half((unsigned short)(cw2 >> 16)));
                float w3 = __half2float(__ushort_as_half((unsigned short)(cw3 >> 16)));
                #pragma unroll
                for (int p = 0; p < 4; ++p) {
                    float2 f0 = __half22float2(r0.h2[p]);
                    float2 f1 = __half22float2(r1.h2[p]);
                    float2 f2 = __half22float2(r2.h2[p]);
                    float2 f3 = __half22float2(r3.h2[p]);
                    if (USEBN) {
                        f0.x = fmaxf(fmaf(f0.x, sc[2 * p], sh[2 * p]), 0.f);
                        f0.y = fmaxf(fmaf(f0.y, sc[2 * p + 1], sh[2 * p + 1]), 0.f);
                        f1.x = fmaxf(fmaf(f1.x, sc[2 * p], sh[2 * p]), 0.f);
                        f1.y = fmaxf(fmaf(f1.y, sc[2 * p + 1], sh[2 * p + 1]), 0.f);
                        f2.x = fmaxf(fmaf(f2.x, sc[2 * p], sh[2 * p]), 0.f);
                        f2.y = fmaxf(fmaf(f2.y, sc[2 * p + 1], sh[2 * p + 1]), 0.f);
                        f3.x = fmaxf(fmaf(f3.x, sc[2 * p], sh[2 * p]), 0.f);
                        f3.y = fmaxf(fmaf(f3.y, sc[2 * p + 1], sh[2 * p + 1]), 0.f);
                    }
                    acc[2 * p]     = fmaf(w0, f0.x, acc[2 * p]);
                    acc[2 * p + 1] = fmaf(w0, f0.y, acc[2 * p + 1]);
                    acc[2 * p]     = fmaf(w1, f1.x, acc[2 * p]);
                    acc[2 * p + 1] = fmaf(w1, f1.y, acc[2 * p + 1]);
                    acc[2 * p]     = fmaf(w2, f2.x, acc[2 * p]);
                    acc[2 * p + 1] = fmaf(w2, f2.y, acc[2 * p + 1]);
                    acc[2 * p]     = fmaf(w3, f3.x, acc[2 * p]);
                    acc[2 * p + 1] = fmaf(w3, f3.y, acc[2 * p + 1]);
                }
            }
            for (; e + 6 < e1; e += 8) {     // 2 edges per quarter
                unsigned int cw0 = colwt[e];
                unsigned int cw1 = colwt[e + 4];
                H8 r0, r1;
                r0.u = *(const uint4*)(hb + (size_t)(cw0 & 0xffffu) * 256 + loff);
                r1.u = *(const uint4*)(hb + (size_t)(cw1 & 0xffffu) * 256 + loff);
                float w0 = __half2float(__ushort_as_half((unsigned short)(cw0 >> 16)));
                float w1 = __half2float(__ushort_as_half((unsigned short)(cw1 >> 16)));
                #pragma unroll
                for (int p = 0; p < 4; ++p) {
                    float2 f0 = __half22float2(r0.h2[p]);
                    float2 f1 = __half22float2(r1.h2[p]);
                    if (USEBN) {
                        f0.x = fmaxf(fmaf(f0.x, sc[2 * p], sh[2 * p]), 0.f);
                        f0.y = fmaxf(fmaf(f0.y, sc[2 * p + 1], sh[2 * p + 1]), 0.f);
                        f1.x = fmaxf(fmaf(f1.x, sc[2 * p], sh[2 * p]), 0.f);
                        f1.y = fmaxf(fmaf(f1.y, sc[2 * p + 1], sh[2 * p + 1]), 0.f);
                    }
                    acc[2 * p]     = fmaf(w0, f0.x, acc[2 * p]);
                    acc[2 * p + 1] = fmaf(w0, f0.y, acc[2 * p + 1]);
                    acc[2 * p]     = fmaf(w1, f1.x, acc[2 * p]);
                    acc[2 * p + 1] = fmaf(w1, f1.y, acc[2 * p + 1]);
                }
            }
            for (; e < e1; e += 4) {         // 1 edge per quarter
                unsigned int cw = colwt[e];
                H8 r0;
                r0.u = *(const uint4*)(hb + (size_t)(cw & 0xffffu) * 256 + loff);
                float w0 = __half2float(__ushort_as_half((unsigned short)(cw >> 16)));
                #pragma unroll
                for (int p = 0; p < 4; ++p) {
                    float2 f0 = __half22float2(r0.h2[p]);
                    if (USEBN) {
                        f0.x = fmaxf(fmaf(f0.x, sc[2 * p], sh[2 * p]), 0.f);
                        f0.y = fmaxf(fmaf(f0.y, sc[2 * p + 1], sh[2 * p + 1]), 0.f);
                    }
                    acc[2 * p]     = fmaf(w0, f0.x, acc[2 * p]);
                    acc[2 * p + 1] = fmaf(w0, f0.y, acc[2 * p + 1]);
                }
            }
            #pragma unroll
            for (int c = 0; c < 8; ++c) {
                acc[c] += __shfl_xor(acc[c], 16);
                acc[c] += __shfl_xor(acc[c], 32);
            }
            if (q == 0) {
                float a = ALPHA * dinv[i];
                H8 s8, o;
                s8.u = *(const uint4*)(hb + (size_t)i * 256 + loff);
                #pragma unroll
                for (int p = 0; p < 4; ++p) {
                    float2 f = __half22float2(s8.h2[p]);
                    if (USEBN) {
                        f.x = fmaxf(fmaf(f.x, sc[2 * p], sh[2 * p]), 0.f);
                        f.y = fmaxf(fmaf(f.y, sc[2 * p + 1], sh[2 * p + 1]), 0.f);
                    }
                    o.h2[p] = __float22half2_rn(
                        make_float2(f.x - a * acc[2 * p], f.y - a * acc[2 * p + 1]));
                }
                // swizzled LDS write: row w*16+rr, chunk l ^ (rr&7)
                sA[(w * 16 + rr) * 16 + (l ^ (rr & 7))] = o.u;
            }
        }
        // ---------- phase 2: MFMA from own LDS rows (no barrier needed) ----------
        int g2 = lane >> 4;                  // k-group
        half8_t a[4];
        #pragma unroll
        for (int s = 0; s < 4; ++s) {
            int chunk = (s * 4 + g2) ^ (l & 7);
            a[s] = *(const half8_t*)&sA[(w * 16 + l) * 16 + chunk];
        }
        #pragma unroll
        for (int n0 = 0; n0 < 8; ++n0) {
            floatx4 acc = {0.f, 0.f, 0.f, 0.f};
            #pragma unroll
            for (int s = 0; s < 4; ++s) {
                half8_t b = *(const half8_t*)(Bp + ((size_t)(s * 8 + n0) * 64 + lane) * 8);
                acc = __builtin_amdgcn_mfma_f32_16x16x32_f16(a[s], b, acc, 0, 0, 0);
            }
            int col = n0 * 16 + l;
            float bv = bias[col];
            float v0 = acc[0] + bv, v1 = acc[1] + bv, v2 = acc[2] + bv, v3 = acc[3] + bv;
            int r = row0 + g2 * 4;
            if (MODE == 0) {
                __half* oh = (__half*)outv;
                oh[(size_t)r * 128 + col]       = __float2half_rn(v0);
                oh[(size_t)(r + 1) * 128 + col] = __float2half_rn(v1);
                oh[(size_t)(r + 2) * 128 + col] = __float2half_rn(v2);
                oh[(size_t)(r + 3) * 128 + col] = __float2half_rn(v3);
            } else {
                float* of = (float*)outv;
                of[(size_t)r * 128 + col]       = v0;
                of[(size_t)(r + 1) * 128 + col] = v1;
                of[(size_t)(r + 2) * 128 + col] = v2;
                of[(size_t)(r + 3) * 128 + col] = v3;
            }
            if (MODE == 0) {
                float s_ = v0 + v1 + v2 + v3;
                float q_ = v0 * v0 + v1 * v1 + v2 * v2 + v3 * v3;
                s_ += __shfl_xor(s_, 16); s_ += __shfl_xor(s_, 32);
                q_ += __shfl_xor(q_, 16); q_ += __shfl_xor(q_, 32);
                if (lane < 16) { st_s[w][col] = s_; st_q[w][col] = q_; }
            }
        }
    } else if (MODE == 0) {
        if (lane < 16) {
            #pragma unroll
            for (int n0 = 0; n0 < 8; ++n0) {
                st_s[w][n0 * 16 + l] = 0.f;
                st_q[w][n0 * 16 + l] = 0.f;
            }
        }
    }
    if (MODE == 0) {
        __syncthreads();
        if (tid < 128) {
            partial[(size_t)blockIdx.x * 256 + tid] =
                st_s[0][tid] + st_s[1][tid] + st_s[2][tid] + st_s[3][tid];
            partial[(size_t)blockIdx.x * 256 + 128 + tid] =
                st_q[0][tid] + st_q[1][tid] + st_q[2][tid] + st_q[3][tid];
        }
    }
}

// ---------------- BN reduce: 128 blocks, one column each ----------------
__global__ __launch_bounds__(256) void bn_reduce_kernel(
        const float* __restrict__ partial,
        const float* __restrict__ g, const float* __restrict__ bt,
        float* __restrict__ scale, float* __restrict__ shift) {
    __shared__ float ss[256], sq[256];
    int j = blockIdx.x;       // 0..127
    int tid = threadIdx.x;    // 0..255
    float s = 0.f, q = 0.f;
    for (int b = tid; b < GEMM_NBLK; b += 256) {
        s += partial[(size_t)b * 256 + j];
        q += partial[(size_t)b * 256 + 128 + j];
    }
    ss[tid] = s; sq[tid] = q;
    __syncthreads();
    for (int off = 128; off > 0; off >>= 1) {
        if (tid < off) { ss[tid] += ss[tid + off]; sq[tid] += sq[tid + off]; }
        __syncthreads();
    }
    if (tid == 0) {
        float m = ss[0] / (float)N_NODES;
        float v = sq[0] / (float)N_NODES - m * m;
        float sc = g[j] * rsqrtf(v + BN_EPS);
        scale[j] = sc;
        shift[j] = bt[j] - m * sc;
    }
}

// ---------------- launch ----------------

extern "C" void kernel_launch(void* const* d_in, const int* in_sizes, int n_in,
                              void* d_out, int out_size, void* d_ws, size_t ws_size,
                              hipStream_t stream) {
    const float* x   = (const float*)d_in[0];
    const int*   ei  = (const int*)d_in[1];
    const float* W1  = (const float*)d_in[2];
    const float* b1  = (const float*)d_in[3];
    const float* W2  = (const float*)d_in[4];
    const float* b2  = (const float*)d_in[5];
    const float* W3  = (const float*)d_in[6];
    const float* b3  = (const float*)d_in[7];
    const float* g1  = (const float*)d_in[8];
    const float* bt1 = (const float*)d_in[9];
    const float* g2  = (const float*)d_in[10];
    const float* bt2 = (const float*)d_in[11];
    float* out = (float*)d_out;

    const int* row = ei;
    const int* col = ei + N_EDGES;

    char* ws = (char*)d_ws;
    size_t off = 0;
    auto alloc = [&](size_t bytes) -> void* {
        void* p = ws + off;
        off += (bytes + 255) & ~(size_t)255;
        return p;
    };
    int*   rowptr   = (int*)alloc((N_NODES + 1) * 4);
    int*   localscan= (int*)alloc(N_NODES * 4);
    int*   blocksum = (int*)alloc(NB_SCAN * 4);
    float* dinv     = (float*)alloc(N_NODES * 4);
    unsigned int* colwt = (unsigned int*)alloc((size_t)N_EDGES * 4);
    _Float16* Bp    = (_Float16*)alloc(3 * 32768 * 2);
    float* partial  = (float*)alloc((size_t)GEMM_NBLK * 256 * 4);
    float* scale1   = (float*)alloc(F * 4);
    float* shift1   = (float*)alloc(F * 4);
    float* scale2   = (float*)alloc(F * 4);
    float* shift2   = (float*)alloc(F * 4);
    __half* xh      = (__half*)alloc((size_t)N_NODES * F * 2);
    __half* h1      = (__half*)alloc((size_t)N_NODES * F * 2);
    __half* h2      = (__half*)alloc((size_t)N_NODES * F * 2);
    // subhist (64 x 50000 ints = 12.8 MB) aliases h1: dead before fused0 writes h1.
    int* subhist    = (int*)h1;
    (void)ws_size; (void)n_in; (void)in_sizes; (void)out_size;

    prep_kernel<<<NB_X2H + NB_PB + NB_HIST, PREP_THREADS, 0, stream>>>(
        x, xh, W1, W2, W3, Bp, row, subhist);
    scan_block<<<NB_SCAN, 256, 0, stream>>>(subhist, localscan, blocksum, dinv);
    scan_add_tops<<<NB_SCAN, 256, 0, stream>>>(localscan, blocksum, rowptr);
    fill_kernel<<<NB_HIST, PREP_THREADS, 0, stream>>>(row, col, rowptr, subhist,
                                                      dinv, colwt);

    // layer 0: xh -> h1 (fp16) + BN partials
    fused_kernel<0, 0><<<GEMM_NBLK, 256, 0, stream>>>(
        xh, nullptr, nullptr, dinv, rowptr, colwt, Bp, b1, h1, partial);
    bn_reduce_kernel<<<128, 256, 0, stream>>>(partial, g1, bt1, scale1, shift1);

    // layer 1: h1 -> h2 (fp16) + BN partials
    fused_kernel<1, 0><<<GEMM_NBLK, 256, 0, stream>>>(
        h1, scale1, shift1, dinv, rowptr, colwt, Bp + 32768, b2, h2, partial);
    bn_reduce_kernel<<<128, 256, 0, stream>>>(partial, g2, bt2, scale2, shift2);

    // layer 2: h2 -> out (f32)
    fused_kernel<1, 1><<<GEMM_NBLK, 256, 0, stream>>>(
        h2, scale2, shift2, dinv, rowptr, colwt, Bp + 65536, b3, out, nullptr);
}

// Round 12
// 195.942 us; speedup vs baseline: 1.2195x; 1.2195x over previous
//
#include <hip/hip_runtime.h>
#include <hip/hip_fp16.h>

#define N_NODES 50000
#define N_EDGES 800000
#define F 128
#define ALPHA 0.5f
#define BN_EPS 1e-5f
#define NB_SCAN ((N_NODES + 255) / 256)   // 196
#define GEMM_NBLK ((N_NODES + 63) / 64)   // 782
#define NGRP 8
#define GRP_ROWS (N_NODES / NGRP)         // 6250
#define NCHUNK 64
#define CHUNK_I4 (N_EDGES / NCHUNK / 4)   // 3125 int4 per chunk (12500 edges)
#define PREP_THREADS 1024
#define NB_X2H ((N_NODES * F / 8 + PREP_THREADS - 1) / PREP_THREADS)  // 782
#define NB_PB 6
#define NB_HIST (NGRP * NCHUNK)           // 512

typedef _Float16 half8_t __attribute__((ext_vector_type(8)));
typedef float floatx4 __attribute__((ext_vector_type(4)));

union H8 { uint4 u; __half2 h2[4]; };

// ---------------- fused prep: x->fp16 | pack B | LDS-hist counting ----------------
__global__ __launch_bounds__(PREP_THREADS) void prep_kernel(
        const float* __restrict__ x, __half* __restrict__ xh,
        const float* __restrict__ W1, const float* __restrict__ W2,
        const float* __restrict__ W3, _Float16* __restrict__ Bp,
        const int* __restrict__ row, int* __restrict__ subhist) {
    int bid = blockIdx.x;
    if (bid < NB_X2H) {
        int idx = bid * PREP_THREADS + threadIdx.x;   // one per 8 elems
        if (idx < N_NODES * F / 8) {
            float4 f0 = ((const float4*)x)[idx * 2];
            float4 f1 = ((const float4*)x)[idx * 2 + 1];
            H8 o;
            o.h2[0] = __float22half2_rn(make_float2(f0.x, f0.y));
            o.h2[1] = __float22half2_rn(make_float2(f0.z, f0.w));
            o.h2[2] = __float22half2_rn(make_float2(f1.x, f1.y));
            o.h2[3] = __float22half2_rn(make_float2(f1.z, f1.w));
            ((uint4*)xh)[idx] = o.u;
        }
    } else if (bid < NB_X2H + NB_PB) {
        // B[k][n] = W[n][k]; lane holds B[k0+(lane>>4)*8+j][n0*16+(lane&15)]
        int idx = (bid - NB_X2H) * PREP_THREADS + threadIdx.x;   // 3*2048 = 6144
        int layer = idx >> 11;
        int r = idx & 2047;
        int t = r >> 6, lane = r & 63;
        int s = t >> 3, n0 = t & 7;
        int n = n0 * 16 + (lane & 15);
        int k = s * 32 + (lane >> 4) * 8;
        const float* W = (layer == 0) ? W1 : (layer == 1) ? W2 : W3;
        float4 f0 = *(const float4*)(W + n * 128 + k);
        float4 f1 = *(const float4*)(W + n * 128 + k + 4);
        _Float16* dst = Bp + (size_t)layer * 32768 + (size_t)r * 8;
        dst[0] = (_Float16)f0.x; dst[1] = (_Float16)f0.y;
        dst[2] = (_Float16)f0.z; dst[3] = (_Float16)f0.w;
        dst[4] = (_Float16)f1.x; dst[5] = (_Float16)f1.y;
        dst[6] = (_Float16)f1.z; dst[7] = (_Float16)f1.w;
    } else {
        // subhist[c][i] = #edges in chunk c with row i (row-group g only)
        int t = bid - (NB_X2H + NB_PB);
        int g = t & 7, c = t >> 3;
        int rlo = g * GRP_ROWS;
        __shared__ int hist[GRP_ROWS];
        for (int j = threadIdx.x; j < GRP_ROWS; j += PREP_THREADS) hist[j] = 0;
        __syncthreads();
        const int4* r4 = (const int4*)row;
        for (int v = c * CHUNK_I4 + threadIdx.x; v < (c + 1) * CHUNK_I4;
             v += PREP_THREADS) {
            int4 rr = r4[v];
            if ((unsigned)(rr.x - rlo) < GRP_ROWS) atomicAdd(&hist[rr.x - rlo], 1);
            if ((unsigned)(rr.y - rlo) < GRP_ROWS) atomicAdd(&hist[rr.y - rlo], 1);
            if ((unsigned)(rr.z - rlo) < GRP_ROWS) atomicAdd(&hist[rr.z - rlo], 1);
            if ((unsigned)(rr.w - rlo) < GRP_ROWS) atomicAdd(&hist[rr.w - rlo], 1);
        }
        __syncthreads();
        for (int j = threadIdx.x; j < GRP_ROWS; j += PREP_THREADS)
            subhist[(size_t)c * N_NODES + rlo + j] = hist[j];
    }
}

// ---------------- scan: chunk-offsets (in place) + deg/dinv + block scan ----------------

__global__ void scan_block(int* __restrict__ subhist, int* __restrict__ localscan,
                           int* __restrict__ blocksum, float* __restrict__ dinv) {
    __shared__ int s[256];
    int i = blockIdx.x * 256 + threadIdx.x;
    int deg = 0;
    if (i < N_NODES) {
        for (int c = 0; c < NCHUNK; ++c) {
            int t = subhist[(size_t)c * N_NODES + i];
            subhist[(size_t)c * N_NODES + i] = deg;   // exclusive prefix over chunks
            deg += t;
        }
        dinv[i] = deg > 0 ? rsqrtf((float)deg) : 0.f;
    }
    s[threadIdx.x] = deg;
    __syncthreads();
    for (int off = 1; off < 256; off <<= 1) {
        int t = (threadIdx.x >= off) ? s[threadIdx.x - off] : 0;
        __syncthreads();
        s[threadIdx.x] += t;
        __syncthreads();
    }
    if (i < N_NODES) localscan[i] = s[threadIdx.x];
    if (threadIdx.x == 255) blocksum[blockIdx.x] = s[255];
}

__global__ void scan_add_tops(const int* __restrict__ localscan,
                              const int* __restrict__ blocksum,
                              int* __restrict__ rowptr) {
    __shared__ int s[256];
    int v = (threadIdx.x < NB_SCAN) ? blocksum[threadIdx.x] : 0;
    s[threadIdx.x] = v;
    __syncthreads();
    for (int off = 1; off < 256; off <<= 1) {
        int t = (threadIdx.x >= off) ? s[threadIdx.x - off] : 0;
        __syncthreads();
        s[threadIdx.x] += t;
        __syncthreads();
    }
    int base = (blockIdx.x > 0) ? s[blockIdx.x - 1] : 0;
    int i = blockIdx.x * 256 + threadIdx.x;
    if (i < N_NODES) rowptr[i + 1] = localscan[i] + base;
    if (i == 0) rowptr[0] = 0;
}

// ---------------- fill: LDS-cursor counting-sort scatter (no global atomics) ----------------

__global__ __launch_bounds__(PREP_THREADS) void fill_kernel(
        const int* __restrict__ row, const int* __restrict__ col,
        const int* __restrict__ rowptr, const int* __restrict__ chunkoff,
        const float* __restrict__ dinv, unsigned int* __restrict__ colwt) {
    int t = blockIdx.x;           // 512 blocks: g = t&7, c = t>>3
    int g = t & 7, c = t >> 3;
    int rlo = g * GRP_ROWS;
    __shared__ int cur[GRP_ROWS];
    for (int j = threadIdx.x; j < GRP_ROWS; j += PREP_THREADS)
        cur[j] = rowptr[rlo + j] + chunkoff[(size_t)c * N_NODES + rlo + j];
    __syncthreads();
    const int4* r4 = (const int4*)row;
    const int4* c4 = (const int4*)col;
    for (int v = c * CHUNK_I4 + threadIdx.x; v < (c + 1) * CHUNK_I4;
         v += PREP_THREADS) {
        int4 rr = r4[v];
        int4 cc = c4[v];
        int rs[4] = {rr.x, rr.y, rr.z, rr.w};
        int cs[4] = {cc.x, cc.y, cc.z, cc.w};
        #pragma unroll
        for (int k = 0; k < 4; ++k) {
            if ((unsigned)(rs[k] - rlo) < GRP_ROWS) {
                int pos = atomicAdd(&cur[rs[k] - rlo], 1);
                unsigned int hb = __half_as_ushort(__float2half(dinv[cs[k]]));
                colwt[pos] = (unsigned int)cs[k] | (hb << 16);
            }
        }
    }
}

// ---------------- fused high-pass (fp16 rows, quarter-wave per edge) ----------------
// wave per row; quarter q handles edges e0+q, e0+q+4, ...; 4 edges in flight.
template <int USEBN>
__global__ __launch_bounds__(256) void hp_kernel(
        const __half* __restrict__ h,
        const float* __restrict__ scale, const float* __restrict__ shift,
        const float* __restrict__ dinv, const int* __restrict__ rowptr,
        const unsigned int* __restrict__ colwt, __half* __restrict__ out) {
    int lane = threadIdx.x & 63;
    int q = lane >> 4;
    int l = lane & 15;
    int i = blockIdx.x * 4 + (threadIdx.x >> 6);   // 4 waves/block, 1 row each

    float sc[8], sh[8];
    if (USEBN) {
        float4 a0 = ((const float4*)scale)[l * 2];
        float4 a1 = ((const float4*)scale)[l * 2 + 1];
        float4 b0 = ((const float4*)shift)[l * 2];
        float4 b1 = ((const float4*)shift)[l * 2 + 1];
        sc[0] = a0.x; sc[1] = a0.y; sc[2] = a0.z; sc[3] = a0.w;
        sc[4] = a1.x; sc[5] = a1.y; sc[6] = a1.z; sc[7] = a1.w;
        sh[0] = b0.x; sh[1] = b0.y; sh[2] = b0.z; sh[3] = b0.w;
        sh[4] = b1.x; sh[5] = b1.y; sh[6] = b1.z; sh[7] = b1.w;
    }

    int e0 = rowptr[i], e1 = rowptr[i + 1];
    const char* hb = (const char*)h;
    int loff = l * 16;
    float acc[8] = {0.f, 0.f, 0.f, 0.f, 0.f, 0.f, 0.f, 0.f};

    int e = e0 + q;
    for (; e + 14 < e1; e += 16) {   // 4 edges per quarter in flight
        unsigned int cw0 = colwt[e];
        unsigned int cw1 = colwt[e + 4];
        unsigned int cw2 = colwt[e + 8];
        unsigned int cw3 = colwt[e + 12];
        H8 r0, r1, r2, r3;
        r0.u = *(const uint4*)(hb + (size_t)(cw0 & 0xffffu) * 256 + loff);
        r1.u = *(const uint4*)(hb + (size_t)(cw1 & 0xffffu) * 256 + loff);
        r2.u = *(const uint4*)(hb + (size_t)(cw2 & 0xffffu) * 256 + loff);
        r3.u = *(const uint4*)(hb + (size_t)(cw3 & 0xffffu) * 256 + loff);
        float w0 = __half2float(__ushort_as_half((unsigned short)(cw0 >> 16)));
        float w1 = __half2float(__ushort_as_half((unsigned short)(cw1 >> 16)));
        float w2 = __half2float(__ushort_as_half((unsigned short)(cw2 >> 16)));
        float w3 = __half2float(__ushort_as_half((unsigned short)(cw3 >> 16)));
        #pragma unroll
        for (int p = 0; p < 4; ++p) {
            float2 f0 = __half22float2(r0.h2[p]);
            float2 f1 = __half22float2(r1.h2[p]);
            float2 f2 = __half22float2(r2.h2[p]);
            float2 f3 = __half22float2(r3.h2[p]);
            if (USEBN) {
                f0.x = fmaxf(fmaf(f0.x, sc[2 * p], sh[2 * p]), 0.f);
                f0.y = fmaxf(fmaf(f0.y, sc[2 * p + 1], sh[2 * p + 1]), 0.f);
                f1.x = fmaxf(fmaf(f1.x, sc[2 * p], sh[2 * p]), 0.f);
                f1.y = fmaxf(fmaf(f1.y, sc[2 * p + 1], sh[2 * p + 1]), 0.f);
                f2.x = fmaxf(fmaf(f2.x, sc[2 * p], sh[2 * p]), 0.f);
                f2.y = fmaxf(fmaf(f2.y, sc[2 * p + 1], sh[2 * p + 1]), 0.f);
                f3.x = fmaxf(fmaf(f3.x, sc[2 * p], sh[2 * p]), 0.f);
                f3.y = fmaxf(fmaf(f3.y, sc[2 * p + 1], sh[2 * p + 1]), 0.f);
            }
            acc[2 * p]     = fmaf(w0, f0.x, acc[2 * p]);
            acc[2 * p + 1] = fmaf(w0, f0.y, acc[2 * p + 1]);
            acc[2 * p]     = fmaf(w1, f1.x, acc[2 * p]);
            acc[2 * p + 1] = fmaf(w1, f1.y, acc[2 * p + 1]);
            acc[2 * p]     = fmaf(w2, f2.x, acc[2 * p]);
            acc[2 * p + 1] = fmaf(w2, f2.y, acc[2 * p + 1]);
            acc[2 * p]     = fmaf(w3, f3.x, acc[2 * p]);
            acc[2 * p + 1] = fmaf(w3, f3.y, acc[2 * p + 1]);
        }
    }
    for (; e + 6 < e1; e += 8) {     // 2 edges per quarter
        unsigned int cw0 = colwt[e];
        unsigned int cw1 = colwt[e + 4];
        H8 r0, r1;
        r0.u = *(const uint4*)(hb + (size_t)(cw0 & 0xffffu) * 256 + loff);
        r1.u = *(const uint4*)(hb + (size_t)(cw1 & 0xffffu) * 256 + loff);
        float w0 = __half2float(__ushort_as_half((unsigned short)(cw0 >> 16)));
        float w1 = __half2float(__ushort_as_half((unsigned short)(cw1 >> 16)));
        #pragma unroll
        for (int p = 0; p < 4; ++p) {
            float2 f0 = __half22float2(r0.h2[p]);
            float2 f1 = __half22float2(r1.h2[p]);
            if (USEBN) {
                f0.x = fmaxf(fmaf(f0.x, sc[2 * p], sh[2 * p]), 0.f);
                f0.y = fmaxf(fmaf(f0.y, sc[2 * p + 1], sh[2 * p + 1]), 0.f);
                f1.x = fmaxf(fmaf(f1.x, sc[2 * p], sh[2 * p]), 0.f);
                f1.y = fmaxf(fmaf(f1.y, sc[2 * p + 1], sh[2 * p + 1]), 0.f);
            }
            acc[2 * p]     = fmaf(w0, f0.x, acc[2 * p]);
            acc[2 * p + 1] = fmaf(w0, f0.y, acc[2 * p + 1]);
            acc[2 * p]     = fmaf(w1, f1.x, acc[2 * p]);
            acc[2 * p + 1] = fmaf(w1, f1.y, acc[2 * p + 1]);
        }
    }
    for (; e < e1; e += 4) {         // 1 edge per quarter
        unsigned int cw = colwt[e];
        H8 r0;
        r0.u = *(const uint4*)(hb + (size_t)(cw & 0xffffu) * 256 + loff);
        float w0 = __half2float(__ushort_as_half((unsigned short)(cw >> 16)));
        #pragma unroll
        for (int p = 0; p < 4; ++p) {
            float2 f0 = __half22float2(r0.h2[p]);
            if (USEBN) {
                f0.x = fmaxf(fmaf(f0.x, sc[2 * p], sh[2 * p]), 0.f);
                f0.y = fmaxf(fmaf(f0.y, sc[2 * p + 1], sh[2 * p + 1]), 0.f);
            }
            acc[2 * p]     = fmaf(w0, f0.x, acc[2 * p]);
            acc[2 * p + 1] = fmaf(w0, f0.y, acc[2 * p + 1]);
        }
    }

    #pragma unroll
    for (int c = 0; c < 8; ++c) {
        acc[c] += __shfl_xor(acc[c], 16);
        acc[c] += __shfl_xor(acc[c], 32);
    }

    float a = ALPHA * dinv[i];
    if (q == 0) {
        H8 s8, o;
        s8.u = *(const uint4*)(hb + (size_t)i * 256 + loff);
        #pragma unroll
        for (int p = 0; p < 4; ++p) {
            float2 f = __half22float2(s8.h2[p]);
            if (USEBN) {
                f.x = fmaxf(fmaf(f.x, sc[2 * p], sh[2 * p]), 0.f);
                f.y = fmaxf(fmaf(f.y, sc[2 * p + 1], sh[2 * p + 1]), 0.f);
            }
            o.h2[p] = __float22half2_rn(
                make_float2(f.x - a * acc[2 * p], f.y - a * acc[2 * p + 1]));
        }
        *(uint4*)((char*)out + (size_t)i * 256 + loff) = o.u;
    }
}

// ---------------- MFMA GEMM: out[M x 128] = A_half @ B + bias ----------------
// MODE 0: half out + fused BN col partials; MODE 1: f32 out, no stats.
template <int MODE>
__global__ __launch_bounds__(256) void gemm_kernel(
        const __half* __restrict__ A, const _Float16* __restrict__ Bp,
        const float* __restrict__ bias, void* __restrict__ outv,
        float* __restrict__ partial, int M) {
    __shared__ float st_s[4][128];
    __shared__ float st_q[4][128];
    int tid = threadIdx.x;
    int w = tid >> 6, lane = tid & 63;
    int l = lane & 15, g = lane >> 4;
    int row0 = blockIdx.x * 64 + w * 16;
    bool active = row0 < M;   // M % 16 == 0, so waves are all-or-nothing

    const char* Ab = (const char*)A;
    half8_t a[4];
    if (active) {
        #pragma unroll
        for (int s = 0; s < 4; ++s)
            a[s] = *(const half8_t*)(Ab + (size_t)(row0 + l) * 256 + s * 64 + g * 16);
    } else {
        half8_t z = 0;
        a[0] = z; a[1] = z; a[2] = z; a[3] = z;
    }

    #pragma unroll
    for (int n0 = 0; n0 < 8; ++n0) {
        floatx4 acc = {0.f, 0.f, 0.f, 0.f};
        #pragma unroll
        for (int s = 0; s < 4; ++s) {
            half8_t b = *(const half8_t*)(Bp + ((size_t)(s * 8 + n0) * 64 + lane) * 8);
            acc = __builtin_amdgcn_mfma_f32_16x16x32_f16(a[s], b, acc, 0, 0, 0);
        }
        int col = n0 * 16 + l;
        float bv = bias[col];
        float v0 = acc[0] + bv, v1 = acc[1] + bv, v2 = acc[2] + bv, v3 = acc[3] + bv;
        if (active) {
            int r = row0 + g * 4;
            if (MODE == 0) {
                __half* oh = (__half*)outv;
                oh[(size_t)r * 128 + col]       = __float2half_rn(v0);
                oh[(size_t)(r + 1) * 128 + col] = __float2half_rn(v1);
                oh[(size_t)(r + 2) * 128 + col] = __float2half_rn(v2);
                oh[(size_t)(r + 3) * 128 + col] = __float2half_rn(v3);
            } else {
                float* of = (float*)outv;
                of[(size_t)r * 128 + col]       = v0;
                of[(size_t)(r + 1) * 128 + col] = v1;
                of[(size_t)(r + 2) * 128 + col] = v2;
                of[(size_t)(r + 3) * 128 + col] = v3;
            }
        } else {
            v0 = v1 = v2 = v3 = 0.f;
        }
        if (MODE == 0) {
            float s_ = v0 + v1 + v2 + v3;
            float q_ = v0 * v0 + v1 * v1 + v2 * v2 + v3 * v3;
            s_ += __shfl_xor(s_, 16); s_ += __shfl_xor(s_, 32);
            q_ += __shfl_xor(q_, 16); q_ += __shfl_xor(q_, 32);
            if (lane < 16) { st_s[w][col] = s_; st_q[w][col] = q_; }
        }
    }
    if (MODE == 0) {
        __syncthreads();
        if (tid < 128) {
            partial[(size_t)blockIdx.x * 256 + tid] =
                st_s[0][tid] + st_s[1][tid] + st_s[2][tid] + st_s[3][tid];
            partial[(size_t)blockIdx.x * 256 + 128 + tid] =
                st_q[0][tid] + st_q[1][tid] + st_q[2][tid] + st_q[3][tid];
        }
    }
}

// ---------------- BN reduce: 128 blocks, one column each ----------------
__global__ __launch_bounds__(256) void bn_reduce_kernel(
        const float* __restrict__ partial,
        const float* __restrict__ g, const float* __restrict__ bt,
        float* __restrict__ scale, float* __restrict__ shift) {
    __shared__ float ss[256], sq[256];
    int j = blockIdx.x;       // 0..127
    int tid = threadIdx.x;    // 0..255
    float s = 0.f, q = 0.f;
    for (int b = tid; b < GEMM_NBLK; b += 256) {
        s += partial[(size_t)b * 256 + j];
        q += partial[(size_t)b * 256 + 128 + j];
    }
    ss[tid] = s; sq[tid] = q;
    __syncthreads();
    for (int off = 128; off > 0; off >>= 1) {
        if (tid < off) { ss[tid] += ss[tid + off]; sq[tid] += sq[tid + off]; }
        __syncthreads();
    }
    if (tid == 0) {
        float m = ss[0] / (float)N_NODES;
        float v = sq[0] / (float)N_NODES - m * m;
        float sc = g[j] * rsqrtf(v + BN_EPS);
        scale[j] = sc;
        shift[j] = bt[j] - m * sc;
    }
}

// ---------------- launch ----------------

extern "C" void kernel_launch(void* const* d_in, const int* in_sizes, int n_in,
                              void* d_out, int out_size, void* d_ws, size_t ws_size,
                              hipStream_t stream) {
    const float* x   = (const float*)d_in[0];
    const int*   ei  = (const int*)d_in[1];
    const float* W1  = (const float*)d_in[2];
    const float* b1  = (const float*)d_in[3];
    const float* W2  = (const float*)d_in[4];
    const float* b2  = (const float*)d_in[5];
    const float* W3  = (const float*)d_in[6];
    const float* b3  = (const float*)d_in[7];
    const float* g1  = (const float*)d_in[8];
    const float* bt1 = (const float*)d_in[9];
    const float* g2  = (const float*)d_in[10];
    const float* bt2 = (const float*)d_in[11];
    float* out = (float*)d_out;

    const int* row = ei;
    const int* col = ei + N_EDGES;

    char* ws = (char*)d_ws;
    size_t off = 0;
    auto alloc = [&](size_t bytes) -> void* {
        void* p = ws + off;
        off += (bytes + 255) & ~(size_t)255;
        return p;
    };
    int*   rowptr   = (int*)alloc((N_NODES + 1) * 4);
    int*   localscan= (int*)alloc(N_NODES * 4);
    int*   blocksum = (int*)alloc(NB_SCAN * 4);
    float* dinv     = (float*)alloc(N_NODES * 4);
    unsigned int* colwt = (unsigned int*)alloc((size_t)N_EDGES * 4);
    _Float16* Bp    = (_Float16*)alloc(3 * 32768 * 2);
    float* partial  = (float*)alloc((size_t)GEMM_NBLK * 256 * 4);
    float* scale1   = (float*)alloc(F * 4);
    float* shift1   = (float*)alloc(F * 4);
    float* scale2   = (float*)alloc(F * 4);
    float* shift2   = (float*)alloc(F * 4);
    __half* xh      = (__half*)alloc((size_t)N_NODES * F * 2);
    __half* hpA     = (__half*)alloc((size_t)(N_NODES + 64) * F * 2);  // pad for last gemm block
    __half* hB      = (__half*)alloc((size_t)N_NODES * F * 2);
    // subhist (64 x 50000 ints = 12.8 MB) aliases hB: dead before gemm0 writes hB.
    int* subhist    = (int*)hB;
    (void)ws_size; (void)n_in; (void)in_sizes; (void)out_size;

    prep_kernel<<<NB_X2H + NB_PB + NB_HIST, PREP_THREADS, 0, stream>>>(
        x, xh, W1, W2, W3, Bp, row, subhist);
    scan_block<<<NB_SCAN, 256, 0, stream>>>(subhist, localscan, blocksum, dinv);
    scan_add_tops<<<NB_SCAN, 256, 0, stream>>>(localscan, blocksum, rowptr);
    fill_kernel<<<NB_HIST, PREP_THREADS, 0, stream>>>(row, col, rowptr, subhist,
                                                      dinv, colwt);

    const int hp_grid = N_NODES / 4;  // 4 waves/block, 1 row per wave

    // layer 0
    hp_kernel<0><<<hp_grid, 256, 0, stream>>>(xh, nullptr, nullptr, dinv, rowptr,
                                              colwt, hpA);
    gemm_kernel<0><<<GEMM_NBLK, 256, 0, stream>>>(hpA, Bp, b1, hB, partial, N_NODES);
    bn_reduce_kernel<<<128, 256, 0, stream>>>(partial, g1, bt1, scale1, shift1);

    // layer 1
    hp_kernel<1><<<hp_grid, 256, 0, stream>>>(hB, scale1, shift1, dinv, rowptr,
                                              colwt, hpA);
    gemm_kernel<0><<<GEMM_NBLK, 256, 0, stream>>>(hpA, Bp + 32768, b2, hB, partial,
                                                  N_NODES);
    bn_reduce_kernel<<<128, 256, 0, stream>>>(partial, g2, bt2, scale2, shift2);

    // layer 2 (output, f32)
    hp_kernel<1><<<hp_grid, 256, 0, stream>>>(hB, scale2, shift2, dinv, rowptr,
                                              colwt, hpA);
    gemm_kernel<1><<<GEMM_NBLK, 256, 0, stream>>>(hpA, Bp + 65536, b3, out, nullptr,
                                                  N_NODES);
}